// Round 4
// baseline (323.267 us; speedup 1.0000x reference)
//
#include <hip/hip_runtime.h>

// Problem constants (fixed by reference setup_inputs)
#define N_ROWS   65536      // 32*2048 flattened rows
#define D        256        // embedding_dim
#define D4       64         // D/4 in float4 units
#define M        1024       // n_embeddings
#define LOSS_OFF 16777216   // d_out offset of loss scalar
#define IDX_OFF  16777217   // d_out offset of indices (as float)
#define COMMIT_SCALE (0.25f / 16777216.0f)  // COMMITMENT_COST / numel(x)
#define E_SCALE  1024.0f    // exact pow2 pre-scale of e so e' in [-1,1]
#define C_SCALE  0.001953125f  // 2/1024: acc*C_SCALE == 2*C exactly

typedef _Float16 f16x8 __attribute__((ext_vector_type(8)));
typedef _Float16 f16x4 __attribute__((ext_vector_type(4)));
typedef float    f32x4 __attribute__((ext_vector_type(4)));

// Async global->LDS DMA, 16 B/lane: LDS dest = base + lane*16 (HW-implicit).
__device__ __forceinline__ void async_copy16(const void* g, void* l) {
    __builtin_amdgcn_global_load_lds(
        (const __attribute__((address_space(1))) unsigned int*)g,
        (__attribute__((address_space(3))) unsigned int*)l, 16, 0, 0);
}

// ===== numpy-exact fp32 row-norm emulation (validated rounds 2-3) =========
__device__ __forceinline__ float np_block128(const float* __restrict__ a, int l) {
    float r0 = __fmul_rn(a[l +   0], a[l +   0]);
    float r1 = __fmul_rn(a[l +  16], a[l +  16]);
    float r2 = __fmul_rn(a[l +  32], a[l +  32]);
    float r3 = __fmul_rn(a[l +  48], a[l +  48]);
    float r4 = __fmul_rn(a[l +  64], a[l +  64]);
    float r5 = __fmul_rn(a[l +  80], a[l +  80]);
    float r6 = __fmul_rn(a[l +  96], a[l +  96]);
    float r7 = __fmul_rn(a[l + 112], a[l + 112]);
    return __fadd_rn(__fadd_rn(__fadd_rn(r0, r1), __fadd_rn(r2, r3)),
                     __fadd_rn(__fadd_rn(r4, r5), __fadd_rn(r6, r7)));
}
__device__ __forceinline__ float np_reduce16(float v) {
    float s = __fadd_rn(v, __shfl_down(v, 8));
    s = __fadd_rn(s, __shfl_down(s, 4));
    s = __fadd_rn(s, __shfl_down(s, 2));
    s = __fadd_rn(s, __shfl_down(s, 1));
    return s;
}

// ---------------- kernel 1: np-exact row norms (coalesced via LDS) --------
__global__ __launch_bounds__(256) void norms_kernel(
    const float4* __restrict__ x4, const float4* __restrict__ emb4,
    float* __restrict__ bsq, float* __restrict__ esq,
    float* __restrict__ loss_slot) {
    __shared__ float rowbuf[16 * 260];   // stride 260: conflict-free np reads
    const int tid = threadIdx.x;
    const float4* src4;
    float* dst;
    int row0;
    if (blockIdx.x < 4096) {
        row0 = blockIdx.x * 16;
        src4 = x4 + (size_t)row0 * 64;
        dst = bsq + row0;
    } else {
        row0 = (blockIdx.x - 4096) * 16;
        src4 = emb4 + (size_t)row0 * 64;
        dst = esq + row0;
    }
    #pragma unroll
    for (int p = 0; p < 4; ++p) {
        const int f = tid + p * 256;     // 0..1023 float4s = 16 rows
        const int r = f >> 6, c4 = f & 63;
        *(float4*)&rowbuf[r * 260 + c4 * 4] = src4[f];
    }
    __syncthreads();
    const int l = tid & 15, g = tid >> 4;
    const float* base = &rowbuf[g * 260];
    const float v0 = np_block128(base, l);
    const float v1 = np_block128(base + 128, l);
    const float t0 = np_reduce16(v0);
    const float t1 = np_reduce16(v1);
    if (l == 0) dst[g] = __fadd_rn(t0, t1);
    if (blockIdx.x == 0 && tid == 0) *loss_slot = 0.0f;  // d_out is poisoned
}

// ---------------- kernel 2: split e' = 1024*e into CHUNKED fp16 planes ----
// Per (kc, jt) chunk of 8 KB (128 codes x 32 k), 16-B granules stored in
// READ order of the argmin kernel:
//   granule g = (code_local>>4)*64 + q*16 + (code_local&15),  q = k-octet.
// Chunk stays contiguous (global_load_lds copies verbatim); argmin B-reads
// are lane-linear (base + lane*16): zero LDS bank conflicts (validated r1).
__global__ __launch_bounds__(256) void esplit_kernel(
    const float4* __restrict__ emb4,
    _Float16* __restrict__ e_hi, _Float16* __restrict__ e_mid) {
    const int f = blockIdx.x * 256 + threadIdx.x;   // 0..65535 float4s
    const int code = f >> 6, k4 = f & 63;
    const int kc = k4 >> 3, k8 = k4 & 7;            // 32-k chunk, octet pos
    const int q = k8 >> 1, half = k8 & 1;           // k-octet, half-granule
    const int jt = code >> 7, cl = code & 127;      // 128-code chunk
    const int cg = cl >> 4, lmc = cl & 15;          // code group / lane slot
    float4 v = emb4[f];
    float a[4] = {v.x * E_SCALE, v.y * E_SCALE, v.z * E_SCALE, v.w * E_SCALE};
    f16x4 hi, mid;
    #pragma unroll
    for (int j = 0; j < 4; ++j) {
        _Float16 h = (_Float16)a[j];
        float r = __fsub_rn(a[j], (float)h);
        hi[j] = h;
        mid[j] = (_Float16)r;
    }
    const size_t ofs = (size_t)kc * 32768 + (size_t)jt * 4096
                     + (size_t)(cg * 64 + q * 16 + lmc) * 8 + half * 4;
    *(f16x4*)&e_hi[ofs]  = hi;
    *(f16x4*)&e_mid[ofs] = mid;
}

// ---------------- kernel 3: fp16-split MFMA distances + argmin ------------
// Block: 64 rows x all 1024 codes; 4 waves 2x2 (wave = 32 rows x 64 codes).
// NEW (this round): register-ping-pong pipeline -- frag reads of chunk c
// issued at sub-step c, MFMA of chunk c runs at sub-step c+1 from registers.
// LDS-read latency (the measured stall: MfmaUtil 32% with all waits removed)
// is hidden under a full MFMA burst. To afford the ping-pong registers at
// the 256-unified-reg / 2-waves-per-SIMD boundary, the A mid-plane moves to
// LDS (written once in prologue, bit-exact f16 round-trip) and its per-kc
// fragments are ping-ponged like B. 2 DMA slots (lead-1: one full sub-step
// ~1250cyc >> L2 latency). Slot index == parity == kc&1 (all static).
// WAR safety: slot (c+1)&1's last readers (sub-step c-1) are complete via
// the fused lgkmcnt(0) before barrier c; DMA(c+1) issues after the barrier.
// MFMA order per accumulator (hi*bh, mid*bh, hi*bm; kc ascending) is
// BIT-IDENTICAL to the validated rounds -> absmax 0 preserved.
__global__ __launch_bounds__(256, 2) void argmin_mfma_kernel(
    const float* __restrict__ x,
    const _Float16* __restrict__ e_hi, const _Float16* __restrict__ e_mid,
    const float* __restrict__ esq, const float* __restrict__ bsq,
    float* __restrict__ idx_out_f, int* __restrict__ idx_out_i) {
    // buf[s]: hi plane f16[0..4096) = granule-permuted chunk, mid at +4096
    __shared__ __attribute__((aligned(16))) _Float16 buf[2][8192];
    // amid[w_row]: A mid-plane frags, frag (fm,kc) at (fm*8+kc)*512 + lane*8
    __shared__ __attribute__((aligned(16))) _Float16 amid[2][8192];
    __shared__ float esq_lds[1024];

    const int tid = threadIdx.x;
    const int w = tid >> 6, lane = tid & 63;
    const int w_row = w >> 1, w_col = w & 1;
    const int lm = lane & 15, q = lane >> 4;     // A/B frag: [lm][k=q*8+j]
    const int row0 = blockIdx.x * 64;
    const int lofs = lane * 8;                   // lane-linear 16 B

    // DMA one (jt,kc) chunk into slot s: 8 KB hi + 8 KB mid; wave w moves
    // bytes [w*2048, w*2048+2048) of each plane via 2 width-16 instrs.
    auto dma = [&](int jtn, int kcn, int s) {
        const size_t gofs = (size_t)kcn * 65536 + (size_t)jtn * 8192
                          + (size_t)w * 2048 + (size_t)lane * 16;   // bytes
        const char* gh = (const char*)e_hi + gofs;
        const char* gm = (const char*)e_mid + gofs;
        _Float16* lh  = &buf[s][w * 1024];          // byte ofs w*2048
        _Float16* lmm = &buf[s][4096 + w * 1024];
        async_copy16(gh, lh);
        async_copy16(gh + 1024, lh + 512);
        async_copy16(gm, lmm);
        async_copy16(gm + 1024, lmm + 512);
    };

    // Chunk 0 DMA first: overlaps the (long) A-frag prologue.
    dma(0, 0, 0);

    // ---- A fragments: rows row0 + w_row*32 + fm*16 + lm. hi plane kept in
    // registers; mid plane written to LDS (only w_col==0 wave of each pair;
    // waves 0/1 and 2/3 compute identical frags). Bit-exact f16 round-trip.
    f16x8 a_hi[2][8];
    #pragma unroll
    for (int fm = 0; fm < 2; ++fm) {
        const float* xr = x + (size_t)(row0 + w_row * 32 + fm * 16 + lm) * D + q * 8;
        #pragma unroll
        for (int kc = 0; kc < 8; ++kc) {
            float4 v0 = *(const float4*)(xr + kc * 32);
            float4 v1 = *(const float4*)(xr + kc * 32 + 4);
            float e[8] = {v0.x, v0.y, v0.z, v0.w, v1.x, v1.y, v1.z, v1.w};
            f16x8 hi, md;
            #pragma unroll
            for (int j = 0; j < 8; ++j) {
                _Float16 h = (_Float16)e[j];
                float r = __fsub_rn(e[j], (float)h);
                hi[j] = h;
                md[j] = (_Float16)r;
            }
            a_hi[fm][kc] = hi;
            if (w_col == 0)
                *(f16x8*)&amid[w_row][(fm * 8 + kc) * 512 + lofs] = md;
        }
    }
    float bq[2][4];
    #pragma unroll
    for (int fm = 0; fm < 2; ++fm)
        #pragma unroll
        for (int r = 0; r < 4; ++r)
            bq[fm][r] = bsq[row0 + w_row * 32 + fm * 16 + q * 4 + r];

    // esq -> LDS (exact copy; epilogue reads use lgkm, never vmcnt)
    *(float4*)&esq_lds[tid * 4] = ((const float4*)esq)[tid];

    // Drain ALL prologue vmem (x, bsq, esq loads and dma0): from here on the
    // only outstanding vmem ops are chunk DMAs.
    asm volatile("s_waitcnt vmcnt(0)" ::: "memory");

    float best[2][4] = {{3.0e38f, 3.0e38f, 3.0e38f, 3.0e38f},
                        {3.0e38f, 3.0e38f, 3.0e38f, 3.0e38f}};
    int bidx[2][4] = {{0, 0, 0, 0}, {0, 0, 0, 0}};
    f32x4 acc[2][4] = {};
    f16x8 bh[2][4], bm[2][4], am[2][2];   // [parity][...] ping-pong frags

#define MFMA_TRIPLES(P, KCP)                                                  \
    do {                                                                      \
        __builtin_amdgcn_s_setprio(1);                                        \
        _Pragma("unroll")                                                     \
        for (int fm = 0; fm < 2; ++fm)                                        \
            _Pragma("unroll")                                                 \
            for (int fn = 0; fn < 4; ++fn) {                                  \
                acc[fm][fn] = __builtin_amdgcn_mfma_f32_16x16x32_f16(         \
                    a_hi[fm][(KCP)], bh[(P)][fn], acc[fm][fn], 0, 0, 0);      \
                acc[fm][fn] = __builtin_amdgcn_mfma_f32_16x16x32_f16(         \
                    am[(P)][fm],     bh[(P)][fn], acc[fm][fn], 0, 0, 0);      \
                acc[fm][fn] = __builtin_amdgcn_mfma_f32_16x16x32_f16(         \
                    a_hi[fm][(KCP)], bm[(P)][fn], acc[fm][fn], 0, 0, 0);      \
            }                                                                 \
        __builtin_amdgcn_s_setprio(0);                                        \
    } while (0)

#define EPILOGUE(JT)                                                          \
    do {                                                                      \
        const int j0e = (JT) * 128;                                           \
        _Pragma("unroll")                                                     \
        for (int fn = 0; fn < 4; ++fn) {                                      \
            const int j = j0e + w_col * 64 + fn * 16 + lm;                    \
            const float eq = esq_lds[j];                                      \
            _Pragma("unroll")                                                 \
            for (int fm = 0; fm < 2; ++fm)                                    \
                _Pragma("unroll")                                             \
                for (int r = 0; r < 4; ++r) {                                 \
                    const float d = __fsub_rn(__fadd_rn(eq, bq[fm][r]),       \
                                              acc[fm][fn][r] * C_SCALE);      \
                    if (d < best[fm][r]) { best[fm][r] = d; bidx[fm][r] = j; }\
                }                                                             \
        }                                                                     \
        _Pragma("unroll")                                                     \
        for (int fm = 0; fm < 2; ++fm)                                        \
            _Pragma("unroll")                                                 \
            for (int fn = 0; fn < 4; ++fn)                                    \
                _Pragma("unroll")                                             \
                for (int r = 0; r < 4; ++r) acc[fm][fn][r] = 0.0f;            \
    } while (0)

    for (int jt = 0; jt < 8; ++jt) {
        #pragma unroll
        for (int kc = 0; kc < 8; ++kc) {
            // vmcnt(0): chunk c's DMA (issued one sub-step ago, ~1250 cyc)
            //           retired -> slot kc&1 full for every wave at barrier.
            // lgkmcnt(0): own frag reads of chunk c-1 done (MFMA operands
            //           valid; also WAR-clears slot (kc+1)&1 for the DMA).
            asm volatile("s_waitcnt vmcnt(0) lgkmcnt(0)\n\t"
                         "s_barrier" ::: "memory");
            __builtin_amdgcn_sched_barrier(0);   // rule-18 guard
            // DMA chunk c+1 into slot (kc+1)&1 (8(jt+1) is even -> slot 0)
            if (kc < 7)       dma(jt, kc + 1, (kc + 1) & 1);
            else if (jt < 7)  dma(jt + 1, 0, 0);
            // Frag reads of chunk c -> parity kc&1 (slot == parity). Issued
            // here, consumed NEXT sub-step: latency hidden under MFMAs.
            {
                const int P = kc & 1;
                #pragma unroll
                for (int fn = 0; fn < 4; ++fn) {
                    const int bo = (w_col * 4 + fn) * 512 + lofs;
                    bh[P][fn] = *(const f16x8*)&buf[P][bo];
                    bm[P][fn] = *(const f16x8*)&buf[P][4096 + bo];
                }
                #pragma unroll
                for (int fm = 0; fm < 2; ++fm)
                    am[P][fm] = *(const f16x8*)
                        &amid[w_row][(fm * 8 + kc) * 512 + lofs];
            }
            // MFMA chunk c-1 from the other parity (registers, no LDS wait).
            if (kc == 0) {
                if (jt) {
                    MFMA_TRIPLES(1, 7);
                    EPILOGUE(jt - 1);
                }
            } else {
                MFMA_TRIPLES((kc - 1) & 1, kc - 1);
            }
        }
    }
    // Tail: chunk 63 (parity 1), then final jt=7 argmin epilogue.
    asm volatile("s_waitcnt lgkmcnt(0)" ::: "memory");
    __builtin_amdgcn_sched_barrier(0);
    MFMA_TRIPLES(1, 7);
    EPILOGUE(7);
#undef MFMA_TRIPLES
#undef EPILOGUE

    // Reduce across the 16 col-lanes of each quad (lexicographic min)
    #pragma unroll
    for (int fm = 0; fm < 2; ++fm)
        #pragma unroll
        for (int r = 0; r < 4; ++r) {
            float d = best[fm][r]; int i = bidx[fm][r];
            #pragma unroll
            for (int mv = 1; mv <= 8; mv <<= 1) {
                const float d2 = __shfl_xor(d, mv, 64);
                const int   i2 = __shfl_xor(i, mv, 64);
                if (d2 < d || (d2 == d && i2 < i)) { d = d2; i = i2; }
            }
            best[fm][r] = d; bidx[fm][r] = i;
        }
    // Cross-wave reduction: overlay scratch onto buf (all buf reads are
    // complete: own reads via the tail lgkmcnt(0), all waves via barrier).
    float* red_d = (float*)&buf[0][0];     // [64][2] floats
    int*   red_i = (int*)&buf[0][256];     // [64][2] ints (byte ofs 512)
    __syncthreads();
    if (lm == 0) {
        #pragma unroll
        for (int fm = 0; fm < 2; ++fm)
            #pragma unroll
            for (int r = 0; r < 4; ++r) {
                const int rl = w_row * 32 + fm * 16 + q * 4 + r;
                red_d[rl * 2 + w_col] = best[fm][r];
                red_i[rl * 2 + w_col] = bidx[fm][r];
            }
    }
    __syncthreads();
    if (tid < 64) {
        float d0 = red_d[tid * 2]; int i0 = red_i[tid * 2];
        const float d1 = red_d[tid * 2 + 1]; const int i1 = red_i[tid * 2 + 1];
        if (d1 < d0 || (d1 == d0 && i1 < i0)) { d0 = d1; i0 = i1; }
        idx_out_f[row0 + tid] = (float)i0;
        idx_out_i[row0 + tid] = i0;
    }
}

// ---------------- kernel 4: gather quantized + commitment loss ------------
__global__ __launch_bounds__(256) void gather_loss_kernel(
    const float4* __restrict__ x4, const float4* __restrict__ emb4,
    const int* __restrict__ idx, float4* __restrict__ q4,
    float* __restrict__ loss_slot) {
    const int base = blockIdx.x * 256 + threadIdx.x;
    float acc = 0.0f;
    #pragma unroll
    for (int i = 0; i < 16; ++i) {
        const int f   = base + i * (1024 * 256);
        const int row = f >> 6;
        const int c4  = f & 63;
        const int e   = idx[row];                  // wave-uniform (64 f4/row)
        float4 qv = emb4[e * D4 + c4];
        float4 xv = x4[f];
        q4[f] = qv;
        const float dx = xv.x - qv.x, dy = xv.y - qv.y;
        const float dz = xv.z - qv.z, dw = xv.w - qv.w;
        acc += dx * dx + dy * dy + dz * dz + dw * dw;
    }
    #pragma unroll
    for (int off = 32; off; off >>= 1) acc += __shfl_down(acc, off, 64);
    __shared__ float wsum[4];
    const int lane = threadIdx.x & 63, w = threadIdx.x >> 6;
    if (lane == 0) wsum[w] = acc;
    __syncthreads();
    if (threadIdx.x == 0) {
        atomicAdd(loss_slot, (wsum[0] + wsum[1] + wsum[2] + wsum[3]) * COMMIT_SCALE);
    }
}

extern "C" void kernel_launch(void* const* d_in, const int* in_sizes, int n_in,
                              void* d_out, int out_size, void* d_ws, size_t ws_size,
                              hipStream_t stream) {
    const float* x   = (const float*)d_in[0];    // 32*2048*256
    const float* emb = (const float*)d_in[1];    // 1024*256
    float* out = (float*)d_out;
    // ws layout (16B-aligned): bsq | esq | idx | e_hi(chunked) | e_mid(chunked)
    float*    bsq  = (float*)d_ws;                       // N_ROWS f32
    float*    esq  = bsq + N_ROWS;                       // M f32
    int*      idx  = (int*)(esq + M);                    // N_ROWS i32
    _Float16* e_hi = (_Float16*)(idx + N_ROWS);          // M*D f16 chunked
    _Float16* e_mid = e_hi + (size_t)M * D;              // M*D f16 chunked

    norms_kernel<<<4096 + M / 16, 256, 0, stream>>>((const float4*)x,
                                                    (const float4*)emb,
                                                    bsq, esq, out + LOSS_OFF);
    esplit_kernel<<<M * D / 4 / 256, 256, 0, stream>>>((const float4*)emb,
                                                       e_hi, e_mid);
    argmin_mfma_kernel<<<N_ROWS / 64, 256, 0, stream>>>(x, e_hi, e_mid,
                                                        esq, bsq,
                                                        out + IDX_OFF, idx);
    gather_loss_kernel<<<1024, 256, 0, stream>>>((const float4*)x,
                                                 (const float4*)emb, idx,
                                                 (float4*)out, out + LOSS_OFF);
}

// Round 5
// 267.720 us; speedup vs baseline: 1.2075x; 1.2075x over previous
//
#include <hip/hip_runtime.h>

// Problem constants (fixed by reference setup_inputs)
#define N_ROWS   65536      // 32*2048 flattened rows
#define D        256        // embedding_dim
#define D4       64         // D/4 in float4 units
#define M        1024       // n_embeddings
#define LOSS_OFF 16777216   // d_out offset of loss scalar
#define IDX_OFF  16777217   // d_out offset of indices (as float)
#define COMMIT_SCALE (0.25f / 16777216.0f)  // COMMITMENT_COST / numel(x)
#define E_SCALE  1024.0f    // exact pow2 pre-scale of e so e' in [-1,1]
#define C_SCALE  0.001953125f  // 2/1024: acc*C_SCALE == 2*C exactly

typedef _Float16 f16x8 __attribute__((ext_vector_type(8)));
typedef _Float16 f16x4 __attribute__((ext_vector_type(4)));
typedef float    f32x4 __attribute__((ext_vector_type(4)));

// ===== numpy-exact fp32 row-norm emulation (validated rounds 2-3) =========
__device__ __forceinline__ float np_block128(const float* __restrict__ a, int l) {
    float r0 = __fmul_rn(a[l +   0], a[l +   0]);
    float r1 = __fmul_rn(a[l +  16], a[l +  16]);
    float r2 = __fmul_rn(a[l +  32], a[l +  32]);
    float r3 = __fmul_rn(a[l +  48], a[l +  48]);
    float r4 = __fmul_rn(a[l +  64], a[l +  64]);
    float r5 = __fmul_rn(a[l +  80], a[l +  80]);
    float r6 = __fmul_rn(a[l +  96], a[l +  96]);
    float r7 = __fmul_rn(a[l + 112], a[l + 112]);
    return __fadd_rn(__fadd_rn(__fadd_rn(r0, r1), __fadd_rn(r2, r3)),
                     __fadd_rn(__fadd_rn(r4, r5), __fadd_rn(r6, r7)));
}
__device__ __forceinline__ float np_reduce16(float v) {
    float s = __fadd_rn(v, __shfl_down(v, 8));
    s = __fadd_rn(s, __shfl_down(s, 4));
    s = __fadd_rn(s, __shfl_down(s, 2));
    s = __fadd_rn(s, __shfl_down(s, 1));
    return s;
}

// ------- kernel 1: np-exact row norms + (emb branch) fused e-split -------
// 16 rows/block. Phase 1: float4-coalesced load into LDS (exact copy).
// Phase 2: 16-lane groups read LDS in the np AVX-512 order (bit-identical).
// Phase 3 (emb blocks only): split e' = 1024*e into chunked fp16 planes
// straight from rowbuf (exact copies) -- the old esplit kernel, fused here
// to remove one launch gap. Layout per (kc, jt) chunk of 8 KB: 16-B granule
//   g = (code_local>>4)*64 + q*16 + (code_local&15),  q = k-octet,
// so argmin B-fragment loads are lane-linear (validated round 1).
__global__ __launch_bounds__(256) void norms_kernel(
    const float4* __restrict__ x4, const float4* __restrict__ emb4,
    float* __restrict__ bsq, float* __restrict__ esq,
    _Float16* __restrict__ e_hi, _Float16* __restrict__ e_mid,
    float* __restrict__ loss_slot) {
    __shared__ float rowbuf[16 * 260];   // stride 260: conflict-free np reads
    const int tid = threadIdx.x;
    const float4* src4;
    float* dst;
    int row0;
    const bool is_emb = blockIdx.x >= 4096;
    if (!is_emb) {
        row0 = blockIdx.x * 16;
        src4 = x4 + (size_t)row0 * 64;
        dst = bsq + row0;
    } else {
        row0 = (blockIdx.x - 4096) * 16;
        src4 = emb4 + (size_t)row0 * 64;
        dst = esq + row0;
    }
    #pragma unroll
    for (int p = 0; p < 4; ++p) {
        const int f = tid + p * 256;     // 0..1023 float4s = 16 rows
        const int r = f >> 6, c4 = f & 63;
        *(float4*)&rowbuf[r * 260 + c4 * 4] = src4[f];
    }
    __syncthreads();
    const int l = tid & 15, g = tid >> 4;
    const float* base = &rowbuf[g * 260];
    const float v0 = np_block128(base, l);
    const float v1 = np_block128(base + 128, l);
    const float t0 = np_reduce16(v0);
    const float t1 = np_reduce16(v1);
    if (l == 0) dst[g] = __fadd_rn(t0, t1);
    if (blockIdx.x == 0 && tid == 0) *loss_slot = 0.0f;  // d_out is poisoned

    if (is_emb) {
        // Fused esplit: 4 float4s per thread, values from rowbuf (exact).
        #pragma unroll
        for (int p = 0; p < 4; ++p) {
            const int f = tid + p * 256;            // block-local float4 id
            const int r = f >> 6, k4 = f & 63;
            const int code = row0 + r;
            const int kc = k4 >> 3, k8 = k4 & 7;    // 32-k chunk, octet pos
            const int q = k8 >> 1, half = k8 & 1;   // k-octet, half-granule
            const int jt = code >> 7, cl = code & 127;
            const int cg = cl >> 4, lmc = cl & 15;
            float4 v = *(const float4*)&rowbuf[r * 260 + k4 * 4];
            float a[4] = {v.x * E_SCALE, v.y * E_SCALE,
                          v.z * E_SCALE, v.w * E_SCALE};
            f16x4 hi, mid;
            #pragma unroll
            for (int j = 0; j < 4; ++j) {
                _Float16 h = (_Float16)a[j];
                float rr = __fsub_rn(a[j], (float)h);
                hi[j] = h;
                mid[j] = (_Float16)rr;
            }
            const size_t ofs = (size_t)kc * 32768 + (size_t)jt * 4096
                             + (size_t)(cg * 64 + q * 16 + lmc) * 8 + half * 4;
            *(f16x4*)&e_hi[ofs]  = hi;
            *(f16x4*)&e_mid[ofs] = mid;
        }
    }
}

// ---------------- kernel 2: fp16-split MFMA distances + argmin ------------
// Block: 64 rows x all 1024 codes; 4 waves 2x2 (wave = 32 rows x 64 codes).
// NEW (this round): NO LDS staging for B at all. The per-chunk working set
// (16 KB) is L1-resident and the full planes (1 MB) are L2-resident, so each
// wave loads its 8 B-fragments directly global->VGPR (lane-linear chunked
// layout -> one coalesced global_load_dwordx4 each). No barriers in the main
// loop: waves free-run and self-stagger, so one wave's loads overlap another
// wave's MFMAs (the r1/r3 barrier forced all 8 waves/CU into a simultaneous
// ds_read burst -- pipes alternated instead of overlapping, MfmaUtil 32%).
// Register budget stays at the validated r3 level (no ping-pong arrays --
// the r4 spill lesson); compiler handles cross-chunk ILP within its budget.
// MFMA order per accumulator (hi*bh, mid*bh, hi*bm; fn inner, kc ascending,
// jt ascending) is BIT-IDENTICAL to validated rounds -> absmax 0 preserved.
__global__ __launch_bounds__(256, 2) void argmin_mfma_kernel(
    const float* __restrict__ x,
    const _Float16* __restrict__ e_hi, const _Float16* __restrict__ e_mid,
    const float* __restrict__ esq, const float* __restrict__ bsq,
    float* __restrict__ idx_out_f, int* __restrict__ idx_out_i) {
    __shared__ float esq_lds[1024];
    __shared__ float red_d[64][2];
    __shared__ int   red_i[64][2];

    const int tid = threadIdx.x;
    const int w = tid >> 6, lane = tid & 63;
    const int w_row = w >> 1, w_col = w & 1;
    const int lm = lane & 15, q = lane >> 4;     // A/B frag: [lm][k=q*8+j]
    const int row0 = blockIdx.x * 64;

    // ---- A fragments: rows row0 + w_row*32 + fm*16 + lm, split on the fly
    f16x8 a_hi[2][8], a_mid[2][8];
    #pragma unroll
    for (int fm = 0; fm < 2; ++fm) {
        const float* xr = x + (size_t)(row0 + w_row * 32 + fm * 16 + lm) * D + q * 8;
        #pragma unroll
        for (int kc = 0; kc < 8; ++kc) {
            float4 v0 = *(const float4*)(xr + kc * 32);
            float4 v1 = *(const float4*)(xr + kc * 32 + 4);
            float e[8] = {v0.x, v0.y, v0.z, v0.w, v1.x, v1.y, v1.z, v1.w};
            #pragma unroll
            for (int j = 0; j < 8; ++j) {
                _Float16 h = (_Float16)e[j];
                float r = __fsub_rn(e[j], (float)h);
                a_hi[fm][kc][j]  = h;
                a_mid[fm][kc][j] = (_Float16)r;
            }
        }
    }
    float bq[2][4];
    #pragma unroll
    for (int fm = 0; fm < 2; ++fm)
        #pragma unroll
        for (int r = 0; r < 4; ++r)
            bq[fm][r] = bsq[row0 + w_row * 32 + fm * 16 + q * 4 + r];

    // esq -> LDS once (exact copy); epilogue reads hit LDS, not global.
    *(float4*)&esq_lds[tid * 4] = ((const float4*)esq)[tid];
    __syncthreads();                      // the ONLY pre-reduction barrier

    float best[2][4] = {{3.0e38f, 3.0e38f, 3.0e38f, 3.0e38f},
                        {3.0e38f, 3.0e38f, 3.0e38f, 3.0e38f}};
    int bidx[2][4] = {{0, 0, 0, 0}, {0, 0, 0, 0}};

    const int fofs = (w_col * 4) * 512 + lane * 8;   // f16 units
    for (int jt = 0; jt < 8; ++jt) {
        const int j0 = jt * 128;
        f32x4 acc[2][4] = {};
        #pragma unroll
        for (int kc = 0; kc < 8; ++kc) {
            // B fragments straight from global (L1/L2-hot, coalesced 16 B).
            const size_t cb = (size_t)kc * 32768 + (size_t)jt * 4096 + fofs;
            f16x8 bh[4], bm[4];
            #pragma unroll
            for (int fn = 0; fn < 4; ++fn) {
                bh[fn] = *(const f16x8*)&e_hi[cb + fn * 512];
                bm[fn] = *(const f16x8*)&e_mid[cb + fn * 512];
            }
            #pragma unroll
            for (int fm = 0; fm < 2; ++fm)
                #pragma unroll
                for (int fn = 0; fn < 4; ++fn) {
                    acc[fm][fn] = __builtin_amdgcn_mfma_f32_16x16x32_f16(
                        a_hi[fm][kc], bh[fn], acc[fm][fn], 0, 0, 0);
                    acc[fm][fn] = __builtin_amdgcn_mfma_f32_16x16x32_f16(
                        a_mid[fm][kc], bh[fn], acc[fm][fn], 0, 0, 0);
                    acc[fm][fn] = __builtin_amdgcn_mfma_f32_16x16x32_f16(
                        a_hi[fm][kc], bm[fn], acc[fm][fn], 0, 0, 0);
                }
        }
        // Epilogue: reference-rounded d, running argmin (ascending j, strict <)
        #pragma unroll
        for (int fn = 0; fn < 4; ++fn) {
            const int j = j0 + w_col * 64 + fn * 16 + lm;
            const float eq = esq_lds[j];
            #pragma unroll
            for (int fm = 0; fm < 2; ++fm)
                #pragma unroll
                for (int r = 0; r < 4; ++r) {
                    const float d = __fsub_rn(__fadd_rn(eq, bq[fm][r]),
                                              acc[fm][fn][r] * C_SCALE);
                    if (d < best[fm][r]) { best[fm][r] = d; bidx[fm][r] = j; }
                }
        }
    }
    // Reduce across the 16 col-lanes of each quad (lexicographic min)
    #pragma unroll
    for (int fm = 0; fm < 2; ++fm)
        #pragma unroll
        for (int r = 0; r < 4; ++r) {
            float d = best[fm][r]; int i = bidx[fm][r];
            #pragma unroll
            for (int mv = 1; mv <= 8; mv <<= 1) {
                const float d2 = __shfl_xor(d, mv, 64);
                const int   i2 = __shfl_xor(i, mv, 64);
                if (d2 < d || (d2 == d && i2 < i)) { d = d2; i = i2; }
            }
            best[fm][r] = d; bidx[fm][r] = i;
        }
    __syncthreads();
    if (lm == 0) {
        #pragma unroll
        for (int fm = 0; fm < 2; ++fm)
            #pragma unroll
            for (int r = 0; r < 4; ++r) {
                const int rl = w_row * 32 + fm * 16 + q * 4 + r;
                red_d[rl][w_col] = best[fm][r];
                red_i[rl][w_col] = bidx[fm][r];
            }
    }
    __syncthreads();
    if (tid < 64) {
        float d0 = red_d[tid][0]; int i0 = red_i[tid][0];
        const float d1 = red_d[tid][1]; const int i1 = red_i[tid][1];
        if (d1 < d0 || (d1 == d0 && i1 < i0)) { d0 = d1; i0 = i1; }
        idx_out_f[row0 + tid] = (float)i0;
        idx_out_i[row0 + tid] = i0;
    }
}

// ---------------- kernel 3: gather quantized + commitment loss ------------
__global__ __launch_bounds__(256) void gather_loss_kernel(
    const float4* __restrict__ x4, const float4* __restrict__ emb4,
    const int* __restrict__ idx, float4* __restrict__ q4,
    float* __restrict__ loss_slot) {
    const int base = blockIdx.x * 256 + threadIdx.x;
    float acc = 0.0f;
    #pragma unroll
    for (int i = 0; i < 16; ++i) {
        const int f   = base + i * (1024 * 256);
        const int row = f >> 6;
        const int c4  = f & 63;
        const int e   = idx[row];                  // wave-uniform (64 f4/row)
        float4 qv = emb4[e * D4 + c4];
        float4 xv = x4[f];
        q4[f] = qv;
        const float dx = xv.x - qv.x, dy = xv.y - qv.y;
        const float dz = xv.z - qv.z, dw = xv.w - qv.w;
        acc += dx * dx + dy * dy + dz * dz + dw * dw;
    }
    #pragma unroll
    for (int off = 32; off; off >>= 1) acc += __shfl_down(acc, off, 64);
    __shared__ float wsum[4];
    const int lane = threadIdx.x & 63, w = threadIdx.x >> 6;
    if (lane == 0) wsum[w] = acc;
    __syncthreads();
    if (threadIdx.x == 0) {
        atomicAdd(loss_slot, (wsum[0] + wsum[1] + wsum[2] + wsum[3]) * COMMIT_SCALE);
    }
}

extern "C" void kernel_launch(void* const* d_in, const int* in_sizes, int n_in,
                              void* d_out, int out_size, void* d_ws, size_t ws_size,
                              hipStream_t stream) {
    const float* x   = (const float*)d_in[0];    // 32*2048*256
    const float* emb = (const float*)d_in[1];    // 1024*256
    float* out = (float*)d_out;
    // ws layout (16B-aligned): bsq | esq | idx | e_hi(chunked) | e_mid(chunked)
    float*    bsq  = (float*)d_ws;                       // N_ROWS f32
    float*    esq  = bsq + N_ROWS;                       // M f32
    int*      idx  = (int*)(esq + M);                    // N_ROWS i32
    _Float16* e_hi = (_Float16*)(idx + N_ROWS);          // M*D f16 chunked
    _Float16* e_mid = e_hi + (size_t)M * D;              // M*D f16 chunked

    norms_kernel<<<4096 + M / 16, 256, 0, stream>>>((const float4*)x,
                                                    (const float4*)emb,
                                                    bsq, esq, e_hi, e_mid,
                                                    out + LOSS_OFF);
    argmin_mfma_kernel<<<N_ROWS / 64, 256, 0, stream>>>(x, e_hi, e_mid,
                                                        esq, bsq,
                                                        out + IDX_OFF, idx);
    gather_loss_kernel<<<1024, 256, 0, stream>>>((const float4*)x,
                                                 (const float4*)emb, idx,
                                                 (float4*)out, out + LOSS_OFF);
}

// Round 6
// 244.874 us; speedup vs baseline: 1.3201x; 1.0933x over previous
//
#include <hip/hip_runtime.h>

// Problem constants (fixed by reference setup_inputs)
#define N_ROWS   65536      // 32*2048 flattened rows
#define D        256        // embedding_dim
#define D4       64         // D/4 in float4 units
#define M        1024       // n_embeddings
#define LOSS_OFF 16777216   // d_out offset of loss scalar
#define IDX_OFF  16777217   // d_out offset of indices (as float)
#define COMMIT_SCALE (0.25f / 16777216.0f)  // COMMITMENT_COST / numel(x)
#define E_SCALE  1024.0f    // exact pow2 pre-scale of e so e' in [-1,1]
#define C_SCALE  0.001953125f  // 2/1024: acc*C_SCALE == 2*C exactly

typedef _Float16 f16x8 __attribute__((ext_vector_type(8)));
typedef _Float16 f16x4 __attribute__((ext_vector_type(4)));
typedef float    f32x4 __attribute__((ext_vector_type(4)));

// Async global->LDS DMA, 16 B/lane: LDS dest = base + lane*16 (HW-implicit).
__device__ __forceinline__ void async_copy16(const void* g, void* l) {
    __builtin_amdgcn_global_load_lds(
        (const __attribute__((address_space(1))) unsigned int*)g,
        (__attribute__((address_space(3))) unsigned int*)l, 16, 0, 0);
}

// ===== numpy-exact fp32 row-norm emulation (validated rounds 2-3) =========
__device__ __forceinline__ float np_block128(const float* __restrict__ a, int l) {
    float r0 = __fmul_rn(a[l +   0], a[l +   0]);
    float r1 = __fmul_rn(a[l +  16], a[l +  16]);
    float r2 = __fmul_rn(a[l +  32], a[l +  32]);
    float r3 = __fmul_rn(a[l +  48], a[l +  48]);
    float r4 = __fmul_rn(a[l +  64], a[l +  64]);
    float r5 = __fmul_rn(a[l +  80], a[l +  80]);
    float r6 = __fmul_rn(a[l +  96], a[l +  96]);
    float r7 = __fmul_rn(a[l + 112], a[l + 112]);
    return __fadd_rn(__fadd_rn(__fadd_rn(r0, r1), __fadd_rn(r2, r3)),
                     __fadd_rn(__fadd_rn(r4, r5), __fadd_rn(r6, r7)));
}
__device__ __forceinline__ float np_reduce16(float v) {
    float s = __fadd_rn(v, __shfl_down(v, 8));
    s = __fadd_rn(s, __shfl_down(s, 4));
    s = __fadd_rn(s, __shfl_down(s, 2));
    s = __fadd_rn(s, __shfl_down(s, 1));
    return s;
}

// ------- kernel 1: np-exact row norms + (emb branch) fused e-split -------
// (unchanged from round 5 -- validated absmax 0)
__global__ __launch_bounds__(256) void norms_kernel(
    const float4* __restrict__ x4, const float4* __restrict__ emb4,
    float* __restrict__ bsq, float* __restrict__ esq,
    _Float16* __restrict__ e_hi, _Float16* __restrict__ e_mid,
    float* __restrict__ loss_slot) {
    __shared__ float rowbuf[16 * 260];   // stride 260: conflict-free np reads
    const int tid = threadIdx.x;
    const float4* src4;
    float* dst;
    int row0;
    const bool is_emb = blockIdx.x >= 4096;
    if (!is_emb) {
        row0 = blockIdx.x * 16;
        src4 = x4 + (size_t)row0 * 64;
        dst = bsq + row0;
    } else {
        row0 = (blockIdx.x - 4096) * 16;
        src4 = emb4 + (size_t)row0 * 64;
        dst = esq + row0;
    }
    #pragma unroll
    for (int p = 0; p < 4; ++p) {
        const int f = tid + p * 256;     // 0..1023 float4s = 16 rows
        const int r = f >> 6, c4 = f & 63;
        *(float4*)&rowbuf[r * 260 + c4 * 4] = src4[f];
    }
    __syncthreads();
    const int l = tid & 15, g = tid >> 4;
    const float* base = &rowbuf[g * 260];
    const float v0 = np_block128(base, l);
    const float v1 = np_block128(base + 128, l);
    const float t0 = np_reduce16(v0);
    const float t1 = np_reduce16(v1);
    if (l == 0) dst[g] = __fadd_rn(t0, t1);
    if (blockIdx.x == 0 && tid == 0) *loss_slot = 0.0f;  // d_out is poisoned

    if (is_emb) {
        // Fused esplit: 4 float4s per thread, values from rowbuf (exact).
        #pragma unroll
        for (int p = 0; p < 4; ++p) {
            const int f = tid + p * 256;            // block-local float4 id
            const int r = f >> 6, k4 = f & 63;
            const int code = row0 + r;
            const int kc = k4 >> 3, k8 = k4 & 7;    // 32-k chunk, octet pos
            const int q = k8 >> 1, half = k8 & 1;   // k-octet, half-granule
            const int jt = code >> 7, cl = code & 127;
            const int cg = cl >> 4, lmc = cl & 15;
            float4 v = *(const float4*)&rowbuf[r * 260 + k4 * 4];
            float a[4] = {v.x * E_SCALE, v.y * E_SCALE,
                          v.z * E_SCALE, v.w * E_SCALE};
            f16x4 hi, mid;
            #pragma unroll
            for (int j = 0; j < 4; ++j) {
                _Float16 h = (_Float16)a[j];
                float rr = __fsub_rn(a[j], (float)h);
                hi[j] = h;
                mid[j] = (_Float16)rr;
            }
            const size_t ofs = (size_t)kc * 32768 + (size_t)jt * 4096
                             + (size_t)(cg * 64 + q * 16 + lmc) * 8 + half * 4;
            *(f16x4*)&e_hi[ofs]  = hi;
            *(f16x4*)&e_mid[ofs] = mid;
        }
    }
}

// ---------------- kernel 2: fp16-split MFMA distances + argmin ------------
// Block: 64 rows x all 1024 codes; 4 waves 2x2 (wave = 32 rows x 64 codes).
// NEW (this round): BARRIER-FREE wave-private pipeline. Each wave only reads
// its w_col half (8 KB) of each 16 KB chunk, so each wave owns a PRIVATE
// double-buffered LDS region and its own DMA stream. Per chunk:
//   ds_read frags -> lgkmcnt(0) -> DMA(c+2) into the just-freed private slot
//   -> MFMA burst -> vmcnt(8) (counted: DMA(c+1) landed; never drains to 0).
// No inter-wave sync in the main loop: waves drift freely, so one wave's
// ds-read stall hides under another wave's MFMA burst (r1/r3's per-chunk
// s_barrier forced all 8 waves/CU into simultaneous ds_read bursts -- pipes
// alternated, MfmaUtil pinned at ~32%; r5's direct-global variant serialized
// L2 latency instead). Cross-wave WAR impossible (private slots).
// Register budget = r1's validated level (no ping-pong arrays -- r4 lesson).
// MFMA order per accumulator (hi*bh, mid*bh, hi*bm; fn inner, kc ascending,
// jt ascending) is BIT-IDENTICAL to validated rounds -> absmax 0 preserved.
__global__ __launch_bounds__(256, 2) void argmin_mfma_kernel(
    const float* __restrict__ x,
    const _Float16* __restrict__ e_hi, const _Float16* __restrict__ e_mid,
    const float* __restrict__ esq, const float* __restrict__ bsq,
    float* __restrict__ idx_out_f, int* __restrict__ idx_out_i) {
    // buf[w][s]: wave-private slot: hi half 4 KB (f16[0:2048]) + mid half
    // 4 KB (f16[2048:4096]).  4 waves x 2 slots x 8 KB = 64 KB.
    __shared__ __attribute__((aligned(16))) _Float16 buf[4][2][4096];
    __shared__ float esq_lds[1024];
    __shared__ float red_d[64][2];
    __shared__ int   red_i[64][2];

    const int tid = threadIdx.x;
    const int w = tid >> 6, lane = tid & 63;
    const int w_row = w >> 1, w_col = w & 1;
    const int lm = lane & 15, q = lane >> 4;     // A/B frag: [lm][k=q*8+j]
    const int row0 = blockIdx.x * 64;

    // Wave-private DMA of chunk c's w_col half: 4 KB hi + 4 KB mid via
    // 8 width-16 instrs (1 KB each).  LDS dest = uniform base + lane*16.
    auto dma = [&](int c, int s) {
        const int jt = c >> 3, kc = c & 7;
        const size_t gofs = (size_t)kc * 65536 + (size_t)jt * 8192
                          + (size_t)w_col * 4096 + (size_t)lane * 16; // bytes
        const char* gh = (const char*)e_hi + gofs;
        const char* gm = (const char*)e_mid + gofs;
        _Float16* lh  = &buf[w][s][0];
        _Float16* lmm = &buf[w][s][2048];
        async_copy16(gh,        lh);
        async_copy16(gh + 1024, lh + 512);
        async_copy16(gh + 2048, lh + 1024);
        async_copy16(gh + 3072, lh + 1536);
        async_copy16(gm,        lmm);
        async_copy16(gm + 1024, lmm + 512);
        async_copy16(gm + 2048, lmm + 1024);
        async_copy16(gm + 3072, lmm + 1536);
    };

    // Chunk 0 DMA first: its latency hides under the long A-frag prologue.
    dma(0, 0);

    // ---- A fragments: rows row0 + w_row*32 + fm*16 + lm, split on the fly
    f16x8 a_hi[2][8], a_mid[2][8];
    #pragma unroll
    for (int fm = 0; fm < 2; ++fm) {
        const float* xr = x + (size_t)(row0 + w_row * 32 + fm * 16 + lm) * D + q * 8;
        #pragma unroll
        for (int kc = 0; kc < 8; ++kc) {
            float4 v0 = *(const float4*)(xr + kc * 32);
            float4 v1 = *(const float4*)(xr + kc * 32 + 4);
            float e[8] = {v0.x, v0.y, v0.z, v0.w, v1.x, v1.y, v1.z, v1.w};
            #pragma unroll
            for (int j = 0; j < 8; ++j) {
                _Float16 h = (_Float16)e[j];
                float r = __fsub_rn(e[j], (float)h);
                a_hi[fm][kc][j]  = h;
                a_mid[fm][kc][j] = (_Float16)r;
            }
        }
    }
    float bq[2][4];
    #pragma unroll
    for (int fm = 0; fm < 2; ++fm)
        #pragma unroll
        for (int r = 0; r < 4; ++r)
            bq[fm][r] = bsq[row0 + w_row * 32 + fm * 16 + q * 4 + r];

    // esq -> LDS once (exact copy); epilogue reads hit LDS, not global.
    *(float4*)&esq_lds[tid * 4] = ((const float4*)esq)[tid];

    // Drain all prologue vmem (incl. dma0) + the esq ds_write, publish esq.
    asm volatile("s_waitcnt vmcnt(0) lgkmcnt(0)" ::: "memory");
    __syncthreads();                     // the ONLY pre-reduction barrier
    dma(1, 1);                           // chunk 1 in flight (queue = 8)

    float best[2][4] = {{3.0e38f, 3.0e38f, 3.0e38f, 3.0e38f},
                        {3.0e38f, 3.0e38f, 3.0e38f, 3.0e38f}};
    int bidx[2][4] = {{0, 0, 0, 0}, {0, 0, 0, 0}};

    for (int jt = 0; jt < 8; ++jt) {
        const int j0 = jt * 128;
        f32x4 acc[2][4] = {};
        #pragma unroll
        for (int kc = 0; kc < 8; ++kc) {
            const int c = jt * 8 + kc;
            const int P = c & 1;
            // Frag reads from MY private slot P (chunk c guaranteed: end of
            // iter c-1 waited vmcnt(8) with queue [dma(c), dma(c+1)]).
            f16x8 bh[4], bm[4];
            #pragma unroll
            for (int fn = 0; fn < 4; ++fn) {
                bh[fn] = *(const f16x8*)&buf[w][P][fn * 512 + lane * 8];
                bm[fn] = *(const f16x8*)&buf[w][P][2048 + fn * 512 + lane * 8];
            }
            asm volatile("s_waitcnt lgkmcnt(0)" ::: "memory");
            __builtin_amdgcn_sched_barrier(0);   // rule-18 guard
            // Slot P's reads done -> refill it with chunk c+2 (same parity).
            if (c < 62) dma(c + 2, P);
            __builtin_amdgcn_s_setprio(1);
            #pragma unroll
            for (int fm = 0; fm < 2; ++fm)
                #pragma unroll
                for (int fn = 0; fn < 4; ++fn) {
                    acc[fm][fn] = __builtin_amdgcn_mfma_f32_16x16x32_f16(
                        a_hi[fm][kc], bh[fn], acc[fm][fn], 0, 0, 0);
                    acc[fm][fn] = __builtin_amdgcn_mfma_f32_16x16x32_f16(
                        a_mid[fm][kc], bh[fn], acc[fm][fn], 0, 0, 0);
                    acc[fm][fn] = __builtin_amdgcn_mfma_f32_16x16x32_f16(
                        a_hi[fm][kc], bm[fn], acc[fm][fn], 0, 0, 0);
                }
            __builtin_amdgcn_s_setprio(0);
            // Counted wait: dma(c+1) = oldest 8 of 16 outstanding -> next
            // iter's slot is full.  Never drains the queue to 0 mid-loop.
            if (c < 62)
                asm volatile("s_waitcnt vmcnt(8)" ::: "memory");
            else if (c == 62)
                asm volatile("s_waitcnt vmcnt(0)" ::: "memory");
            __builtin_amdgcn_sched_barrier(0);
        }
        // Epilogue: reference-rounded d, running argmin (ascending j, strict <)
        #pragma unroll
        for (int fn = 0; fn < 4; ++fn) {
            const int j = j0 + w_col * 64 + fn * 16 + lm;
            const float eq = esq_lds[j];
            #pragma unroll
            for (int fm = 0; fm < 2; ++fm)
                #pragma unroll
                for (int r = 0; r < 4; ++r) {
                    const float d = __fsub_rn(__fadd_rn(eq, bq[fm][r]),
                                              acc[fm][fn][r] * C_SCALE);
                    if (d < best[fm][r]) { best[fm][r] = d; bidx[fm][r] = j; }
                }
        }
    }
    // Reduce across the 16 col-lanes of each quad (lexicographic min)
    #pragma unroll
    for (int fm = 0; fm < 2; ++fm)
        #pragma unroll
        for (int r = 0; r < 4; ++r) {
            float d = best[fm][r]; int i = bidx[fm][r];
            #pragma unroll
            for (int mv = 1; mv <= 8; mv <<= 1) {
                const float d2 = __shfl_xor(d, mv, 64);
                const int   i2 = __shfl_xor(i, mv, 64);
                if (d2 < d || (d2 == d && i2 < i)) { d = d2; i = i2; }
            }
            best[fm][r] = d; bidx[fm][r] = i;
        }
    __syncthreads();
    if (lm == 0) {
        #pragma unroll
        for (int fm = 0; fm < 2; ++fm)
            #pragma unroll
            for (int r = 0; r < 4; ++r) {
                const int rl = w_row * 32 + fm * 16 + q * 4 + r;
                red_d[rl][w_col] = best[fm][r];
                red_i[rl][w_col] = bidx[fm][r];
            }
    }
    __syncthreads();
    if (tid < 64) {
        float d0 = red_d[tid][0]; int i0 = red_i[tid][0];
        const float d1 = red_d[tid][1]; const int i1 = red_i[tid][1];
        if (d1 < d0 || (d1 == d0 && i1 < i0)) { d0 = d1; i0 = i1; }
        idx_out_f[row0 + tid] = (float)i0;
        idx_out_i[row0 + tid] = i0;
    }
}

// ---------------- kernel 3: gather quantized + commitment loss ------------
__global__ __launch_bounds__(256) void gather_loss_kernel(
    const float4* __restrict__ x4, const float4* __restrict__ emb4,
    const int* __restrict__ idx, float4* __restrict__ q4,
    float* __restrict__ loss_slot) {
    const int base = blockIdx.x * 256 + threadIdx.x;
    float acc = 0.0f;
    #pragma unroll
    for (int i = 0; i < 16; ++i) {
        const int f   = base + i * (1024 * 256);
        const int row = f >> 6;
        const int c4  = f & 63;
        const int e   = idx[row];                  // wave-uniform (64 f4/row)
        float4 qv = emb4[e * D4 + c4];
        float4 xv = x4[f];
        q4[f] = qv;
        const float dx = xv.x - qv.x, dy = xv.y - qv.y;
        const float dz = xv.z - qv.z, dw = xv.w - qv.w;
        acc += dx * dx + dy * dy + dz * dz + dw * dw;
    }
    #pragma unroll
    for (int off = 32; off; off >>= 1) acc += __shfl_down(acc, off, 64);
    __shared__ float wsum[4];
    const int lane = threadIdx.x & 63, w = threadIdx.x >> 6;
    if (lane == 0) wsum[w] = acc;
    __syncthreads();
    if (threadIdx.x == 0) {
        atomicAdd(loss_slot, (wsum[0] + wsum[1] + wsum[2] + wsum[3]) * COMMIT_SCALE);
    }
}

extern "C" void kernel_launch(void* const* d_in, const int* in_sizes, int n_in,
                              void* d_out, int out_size, void* d_ws, size_t ws_size,
                              hipStream_t stream) {
    const float* x   = (const float*)d_in[0];    // 32*2048*256
    const float* emb = (const float*)d_in[1];    // 1024*256
    float* out = (float*)d_out;
    // ws layout (16B-aligned): bsq | esq | idx | e_hi(chunked) | e_mid(chunked)
    float*    bsq  = (float*)d_ws;                       // N_ROWS f32
    float*    esq  = bsq + N_ROWS;                       // M f32
    int*      idx  = (int*)(esq + M);                    // N_ROWS i32
    _Float16* e_hi = (_Float16*)(idx + N_ROWS);          // M*D f16 chunked
    _Float16* e_mid = e_hi + (size_t)M * D;              // M*D f16 chunked

    norms_kernel<<<4096 + M / 16, 256, 0, stream>>>((const float4*)x,
                                                    (const float4*)emb,
                                                    bsq, esq, e_hi, e_mid,
                                                    out + LOSS_OFF);
    argmin_mfma_kernel<<<N_ROWS / 64, 256, 0, stream>>>(x, e_hi, e_mid,
                                                        esq, bsq,
                                                        out + IDX_OFF, idx);
    gather_loss_kernel<<<1024, 256, 0, stream>>>((const float4*)x,
                                                 (const float4*)emb, idx,
                                                 (float4*)out, out + LOSS_OFF);
}

// Round 7
// 234.085 us; speedup vs baseline: 1.3810x; 1.0461x over previous
//
#include <hip/hip_runtime.h>

// Problem constants (fixed by reference setup_inputs)
#define N_ROWS   65536      // 32*2048 flattened rows
#define D        256        // embedding_dim
#define D4       64         // D/4 in float4 units
#define M        1024       // n_embeddings
#define LOSS_OFF 16777216   // d_out offset of loss scalar
#define IDX_OFF  16777217   // d_out offset of indices (as float)
#define COMMIT_SCALE (0.25f / 16777216.0f)  // COMMITMENT_COST / numel(x)
#define E_SCALE  1024.0f    // exact pow2 pre-scale of e so e' in [-1,1]
#define C_SCALE  0.001953125f  // 2/1024: acc*C_SCALE == 2*C exactly

typedef _Float16 f16x8 __attribute__((ext_vector_type(8)));
typedef _Float16 f16x4 __attribute__((ext_vector_type(4)));
typedef float    f32x4 __attribute__((ext_vector_type(4)));

// Async global->LDS DMA, 16 B/lane: LDS dest = base + lane*16 (HW-implicit).
__device__ __forceinline__ void async_copy16(const void* g, void* l) {
    __builtin_amdgcn_global_load_lds(
        (const __attribute__((address_space(1))) unsigned int*)g,
        (__attribute__((address_space(3))) unsigned int*)l, 16, 0, 0);
}

// ===== numpy-exact fp32 row-norm emulation (validated rounds 2-3) =========
__device__ __forceinline__ float np_block128(const float* __restrict__ a, int l) {
    float r0 = __fmul_rn(a[l +   0], a[l +   0]);
    float r1 = __fmul_rn(a[l +  16], a[l +  16]);
    float r2 = __fmul_rn(a[l +  32], a[l +  32]);
    float r3 = __fmul_rn(a[l +  48], a[l +  48]);
    float r4 = __fmul_rn(a[l +  64], a[l +  64]);
    float r5 = __fmul_rn(a[l +  80], a[l +  80]);
    float r6 = __fmul_rn(a[l +  96], a[l +  96]);
    float r7 = __fmul_rn(a[l + 112], a[l + 112]);
    return __fadd_rn(__fadd_rn(__fadd_rn(r0, r1), __fadd_rn(r2, r3)),
                     __fadd_rn(__fadd_rn(r4, r5), __fadd_rn(r6, r7)));
}
__device__ __forceinline__ float np_reduce16(float v) {
    float s = __fadd_rn(v, __shfl_down(v, 8));
    s = __fadd_rn(s, __shfl_down(s, 4));
    s = __fadd_rn(s, __shfl_down(s, 2));
    s = __fadd_rn(s, __shfl_down(s, 1));
    return s;
}

// ------- kernel 1: np-exact row norms + (emb branch) fused e-split -------
// (unchanged from rounds 5/6 -- validated absmax 0)
__global__ __launch_bounds__(256) void norms_kernel(
    const float4* __restrict__ x4, const float4* __restrict__ emb4,
    float* __restrict__ bsq, float* __restrict__ esq,
    _Float16* __restrict__ e_hi, _Float16* __restrict__ e_mid,
    float* __restrict__ loss_slot) {
    __shared__ float rowbuf[16 * 260];   // stride 260: conflict-free np reads
    const int tid = threadIdx.x;
    const float4* src4;
    float* dst;
    int row0;
    const bool is_emb = blockIdx.x >= 4096;
    if (!is_emb) {
        row0 = blockIdx.x * 16;
        src4 = x4 + (size_t)row0 * 64;
        dst = bsq + row0;
    } else {
        row0 = (blockIdx.x - 4096) * 16;
        src4 = emb4 + (size_t)row0 * 64;
        dst = esq + row0;
    }
    #pragma unroll
    for (int p = 0; p < 4; ++p) {
        const int f = tid + p * 256;     // 0..1023 float4s = 16 rows
        const int r = f >> 6, c4 = f & 63;
        *(float4*)&rowbuf[r * 260 + c4 * 4] = src4[f];
    }
    __syncthreads();
    const int l = tid & 15, g = tid >> 4;
    const float* base = &rowbuf[g * 260];
    const float v0 = np_block128(base, l);
    const float v1 = np_block128(base + 128, l);
    const float t0 = np_reduce16(v0);
    const float t1 = np_reduce16(v1);
    if (l == 0) dst[g] = __fadd_rn(t0, t1);
    if (blockIdx.x == 0 && tid == 0) *loss_slot = 0.0f;  // d_out is poisoned

    if (is_emb) {
        // Fused esplit: 4 float4s per thread, values from rowbuf (exact).
        #pragma unroll
        for (int p = 0; p < 4; ++p) {
            const int f = tid + p * 256;            // block-local float4 id
            const int r = f >> 6, k4 = f & 63;
            const int code = row0 + r;
            const int kc = k4 >> 3, k8 = k4 & 7;    // 32-k chunk, octet pos
            const int q = k8 >> 1, half = k8 & 1;   // k-octet, half-granule
            const int jt = code >> 7, cl = code & 127;
            const int cg = cl >> 4, lmc = cl & 15;
            float4 v = *(const float4*)&rowbuf[r * 260 + k4 * 4];
            float a[4] = {v.x * E_SCALE, v.y * E_SCALE,
                          v.z * E_SCALE, v.w * E_SCALE};
            f16x4 hi, mid;
            #pragma unroll
            for (int j = 0; j < 4; ++j) {
                _Float16 h = (_Float16)a[j];
                float rr = __fsub_rn(a[j], (float)h);
                hi[j] = h;
                mid[j] = (_Float16)rr;
            }
            const size_t ofs = (size_t)kc * 32768 + (size_t)jt * 4096
                             + (size_t)(cg * 64 + q * 16 + lmc) * 8 + half * 4;
            *(f16x4*)&e_hi[ofs]  = hi;
            *(f16x4*)&e_mid[ofs] = mid;
        }
    }
}

// ---------------- kernel 2: fp16-split MFMA distances + argmin ------------
// Block: 64 rows x all 1024 codes; 4 waves 2x2 (wave = 32 rows x 64 codes).
// NEW (this round): 2-chunk GROUPS, cooperative (dedup'd) DMA, barrier only
// at group boundaries.  r6 post-mortem: private per-wave DMA duplicated B
// 2x (row-partner waves fetch the same half) -> LDS-write + L2 traffic
// doubled, eating the free-running win.  r1 had dedup'd traffic but a
// per-chunk lockstep barrier.  r7 takes the convex point: per group of 2
// chunks (32 KB slot, double-buffered), ONE fused vmcnt(0)+lgkmcnt(0)
// +s_barrier (the awaited DMA was issued a full group ~1300 cyc earlier ->
// cheap), then each wave DMAs its private PIECE of group g+1 (sub=w>>1,
// plane=w&1: 8 KB, zero duplication), then 2 sub-chunks of
// {8 ds_read -> lgkmcnt(0) -> 48 MFMA} free-run between barriers.
// WAR safety: slot (g+1)&1 holds group g-1 whose readers finished before
// this barrier (own reads forced by the fused lgkmcnt(0); barrier
// publishes).  Fragment bytes + MFMA order (hi*bh, mid*bh, hi*bm; fn inner,
// kc ascending, jt ascending) BIT-IDENTICAL to validated rounds -> absmax 0.
__global__ __launch_bounds__(256, 2) void argmin_mfma_kernel(
    const float* __restrict__ x,
    const _Float16* __restrict__ e_hi, const _Float16* __restrict__ e_mid,
    const float* __restrict__ esq, const float* __restrict__ bsq,
    float* __restrict__ idx_out_f, int* __restrict__ idx_out_i) {
    // buf[s]: one 2-chunk group: sub*8192 + plane*4096 + data (f16 units);
    // within (sub,plane): granule-permuted chunk half, lane-linear reads.
    __shared__ __attribute__((aligned(16))) _Float16 buf[2][16384];
    __shared__ float esq_lds[1024];
    __shared__ float red_d[64][2];
    __shared__ int   red_i[64][2];

    const int tid = threadIdx.x;
    const int w = tid >> 6, lane = tid & 63;
    const int w_row = w >> 1, w_col = w & 1;
    const int lm = lane & 15, q = lane >> 4;     // A/B frag: [lm][k=q*8+j]
    const int row0 = blockIdx.x * 64;

    // Cooperative group DMA: group g = chunks (jt, kc0) and (jt, kc0+1),
    // 32 KB total.  Wave w moves piece (sub = w>>1, plane = w&1): 8 KB via
    // 8 width-16 ops.  No wave fetches any byte another wave fetches.
    const int p_sub = w >> 1, p_plane = w & 1;
    const _Float16* p_src = p_plane ? e_mid : e_hi;
    auto dma_group = [&](int g, int s) {
        const int jt = g >> 2, kc0 = (g & 3) * 2;
        const char* gp = (const char*)p_src
                       + (size_t)(kc0 + p_sub) * 65536 + (size_t)jt * 8192
                       + (size_t)lane * 16;
        _Float16* lp = &buf[s][p_sub * 8192 + p_plane * 4096];
        #pragma unroll
        for (int u = 0; u < 8; ++u)
            async_copy16(gp + u * 1024, lp + u * 512);
    };

    // Group 0 DMA first: its latency hides under the long A-frag prologue.
    dma_group(0, 0);

    // ---- A fragments: rows row0 + w_row*32 + fm*16 + lm, split on the fly
    f16x8 a_hi[2][8], a_mid[2][8];
    #pragma unroll
    for (int fm = 0; fm < 2; ++fm) {
        const float* xr = x + (size_t)(row0 + w_row * 32 + fm * 16 + lm) * D + q * 8;
        #pragma unroll
        for (int kc = 0; kc < 8; ++kc) {
            float4 v0 = *(const float4*)(xr + kc * 32);
            float4 v1 = *(const float4*)(xr + kc * 32 + 4);
            float e[8] = {v0.x, v0.y, v0.z, v0.w, v1.x, v1.y, v1.z, v1.w};
            #pragma unroll
            for (int j = 0; j < 8; ++j) {
                _Float16 h = (_Float16)e[j];
                float r = __fsub_rn(e[j], (float)h);
                a_hi[fm][kc][j]  = h;
                a_mid[fm][kc][j] = (_Float16)r;
            }
        }
    }
    float bq[2][4];
    #pragma unroll
    for (int fm = 0; fm < 2; ++fm)
        #pragma unroll
        for (int r = 0; r < 4; ++r)
            bq[fm][r] = bsq[row0 + w_row * 32 + fm * 16 + q * 4 + r];

    // esq -> LDS once (exact copy); epilogue reads hit LDS, not global.
    *(float4*)&esq_lds[tid * 4] = ((const float4*)esq)[tid];

    // Prologue drain doubles as group-0's boundary: my dma_group(0) ops
    // retired + esq published to all waves.
    asm volatile("s_waitcnt vmcnt(0) lgkmcnt(0)" ::: "memory");
    __syncthreads();

    float best[2][4] = {{3.0e38f, 3.0e38f, 3.0e38f, 3.0e38f},
                        {3.0e38f, 3.0e38f, 3.0e38f, 3.0e38f}};
    int bidx[2][4] = {{0, 0, 0, 0}, {0, 0, 0, 0}};

    for (int jt = 0; jt < 8; ++jt) {
        const int j0 = jt * 128;
        f32x4 acc[2][4] = {};
        #pragma unroll
        for (int gi = 0; gi < 4; ++gi) {
            const int g = jt * 4 + gi;
            if (g) {
                // Group boundary: my group-g DMA (issued at top of g-1,
                // ~1300 cyc ago) retired; my g-1 frag reads done (frees
                // slot (g+1)&1); barrier publishes both block-wide.
                asm volatile("s_waitcnt vmcnt(0) lgkmcnt(0)\n\t"
                             "s_barrier" ::: "memory");
                __builtin_amdgcn_sched_barrier(0);   // rule-18 guard
            }
            if (g < 31) dma_group(g + 1, (g + 1) & 1);
            const int s = g & 1;
            #pragma unroll
            for (int sub = 0; sub < 2; ++sub) {
                const int kc = gi * 2 + sub;
                f16x8 bh[4], bm[4];
                const int fb = sub * 8192 + (w_col * 4) * 512 + lane * 8;
                #pragma unroll
                for (int fn = 0; fn < 4; ++fn) {
                    bh[fn] = *(const f16x8*)&buf[s][fb + fn * 512];
                    bm[fn] = *(const f16x8*)&buf[s][fb + 4096 + fn * 512];
                }
                asm volatile("s_waitcnt lgkmcnt(0)" ::: "memory");
                __builtin_amdgcn_sched_barrier(0);   // rule-18 guard
                __builtin_amdgcn_s_setprio(1);
                #pragma unroll
                for (int fm = 0; fm < 2; ++fm)
                    #pragma unroll
                    for (int fn = 0; fn < 4; ++fn) {
                        acc[fm][fn] = __builtin_amdgcn_mfma_f32_16x16x32_f16(
                            a_hi[fm][kc], bh[fn], acc[fm][fn], 0, 0, 0);
                        acc[fm][fn] = __builtin_amdgcn_mfma_f32_16x16x32_f16(
                            a_mid[fm][kc], bh[fn], acc[fm][fn], 0, 0, 0);
                        acc[fm][fn] = __builtin_amdgcn_mfma_f32_16x16x32_f16(
                            a_hi[fm][kc], bm[fn], acc[fm][fn], 0, 0, 0);
                    }
                __builtin_amdgcn_s_setprio(0);
            }
        }
        // Epilogue: reference-rounded d, running argmin (ascending j, strict <)
        // No vmem here (esq/bq/acc in LDS or registers).
        #pragma unroll
        for (int fn = 0; fn < 4; ++fn) {
            const int j = j0 + w_col * 64 + fn * 16 + lm;
            const float eq = esq_lds[j];
            #pragma unroll
            for (int fm = 0; fm < 2; ++fm)
                #pragma unroll
                for (int r = 0; r < 4; ++r) {
                    const float d = __fsub_rn(__fadd_rn(eq, bq[fm][r]),
                                              acc[fm][fn][r] * C_SCALE);
                    if (d < best[fm][r]) { best[fm][r] = d; bidx[fm][r] = j; }
                }
        }
    }
    // Reduce across the 16 col-lanes of each quad (lexicographic min)
    #pragma unroll
    for (int fm = 0; fm < 2; ++fm)
        #pragma unroll
        for (int r = 0; r < 4; ++r) {
            float d = best[fm][r]; int i = bidx[fm][r];
            #pragma unroll
            for (int mv = 1; mv <= 8; mv <<= 1) {
                const float d2 = __shfl_xor(d, mv, 64);
                const int   i2 = __shfl_xor(i, mv, 64);
                if (d2 < d || (d2 == d && i2 < i)) { d = d2; i = i2; }
            }
            best[fm][r] = d; bidx[fm][r] = i;
        }
    __syncthreads();
    if (lm == 0) {
        #pragma unroll
        for (int fm = 0; fm < 2; ++fm)
            #pragma unroll
            for (int r = 0; r < 4; ++r) {
                const int rl = w_row * 32 + fm * 16 + q * 4 + r;
                red_d[rl][w_col] = best[fm][r];
                red_i[rl][w_col] = bidx[fm][r];
            }
    }
    __syncthreads();
    if (tid < 64) {
        float d0 = red_d[tid][0]; int i0 = red_i[tid][0];
        const float d1 = red_d[tid][1]; const int i1 = red_i[tid][1];
        if (d1 < d0 || (d1 == d0 && i1 < i0)) { d0 = d1; i0 = i1; }
        idx_out_f[row0 + tid] = (float)i0;
        idx_out_i[row0 + tid] = i0;
    }
}

// ---------------- kernel 3: gather quantized + commitment loss ------------
__global__ __launch_bounds__(256) void gather_loss_kernel(
    const float4* __restrict__ x4, const float4* __restrict__ emb4,
    const int* __restrict__ idx, float4* __restrict__ q4,
    float* __restrict__ loss_slot) {
    const int base = blockIdx.x * 256 + threadIdx.x;
    float acc = 0.0f;
    #pragma unroll
    for (int i = 0; i < 16; ++i) {
        const int f   = base + i * (1024 * 256);
        const int row = f >> 6;
        const int c4  = f & 63;
        const int e   = idx[row];                  // wave-uniform (64 f4/row)
        float4 qv = emb4[e * D4 + c4];
        float4 xv = x4[f];
        q4[f] = qv;
        const float dx = xv.x - qv.x, dy = xv.y - qv.y;
        const float dz = xv.z - qv.z, dw = xv.w - qv.w;
        acc += dx * dx + dy * dy + dz * dz + dw * dw;
    }
    #pragma unroll
    for (int off = 32; off; off >>= 1) acc += __shfl_down(acc, off, 64);
    __shared__ float wsum[4];
    const int lane = threadIdx.x & 63, w = threadIdx.x >> 6;
    if (lane == 0) wsum[w] = acc;
    __syncthreads();
    if (threadIdx.x == 0) {
        atomicAdd(loss_slot, (wsum[0] + wsum[1] + wsum[2] + wsum[3]) * COMMIT_SCALE);
    }
}

extern "C" void kernel_launch(void* const* d_in, const int* in_sizes, int n_in,
                              void* d_out, int out_size, void* d_ws, size_t ws_size,
                              hipStream_t stream) {
    const float* x   = (const float*)d_in[0];    // 32*2048*256
    const float* emb = (const float*)d_in[1];    // 1024*256
    float* out = (float*)d_out;
    // ws layout (16B-aligned): bsq | esq | idx | e_hi(chunked) | e_mid(chunked)
    float*    bsq  = (float*)d_ws;                       // N_ROWS f32
    float*    esq  = bsq + N_ROWS;                       // M f32
    int*      idx  = (int*)(esq + M);                    // N_ROWS i32
    _Float16* e_hi = (_Float16*)(idx + N_ROWS);          // M*D f16 chunked
    _Float16* e_mid = e_hi + (size_t)M * D;              // M*D f16 chunked

    norms_kernel<<<4096 + M / 16, 256, 0, stream>>>((const float4*)x,
                                                    (const float4*)emb,
                                                    bsq, esq, e_hi, e_mid,
                                                    out + LOSS_OFF);
    argmin_mfma_kernel<<<N_ROWS / 64, 256, 0, stream>>>(x, e_hi, e_mid,
                                                        esq, bsq,
                                                        out + IDX_OFF, idx);
    gather_loss_kernel<<<1024, 256, 0, stream>>>((const float4*)x,
                                                 (const float4*)emb, idx,
                                                 (float4*)out, out + LOSS_OFF);
}